// Round 1
// baseline (1296.946 us; speedup 1.0000x reference)
//
#include <hip/hip_runtime.h>

#define HD 256
#define KD 512

typedef _Float16 half8 __attribute__((ext_vector_type(8)));
typedef _Float16 half4v __attribute__((ext_vector_type(4)));
typedef float floatx4 __attribute__((ext_vector_type(4)));

__device__ __forceinline__ float sigmf_(float x) { return 1.f / (1.f + __expf(-x)); }
__device__ __forceinline__ float tanhf_(float x) {
  x = fminf(fmaxf(x, -15.f), 15.f);
  float e = __expf(2.f * x);
  return (e - 1.f) / (e + 1.f);
}

// ---------------------------------------------------------------------------
// prep: gate bias sums, leaf c vector, and level-8 folded bias
// bias2[g][n] = bsum[g][n] + sum_k Wg[n][k] * 2*h_leaf[k]  (k < 256, h part)
// ---------------------------------------------------------------------------
__global__ void prep_kernel(const float* __restrict__ bf_, const float* __restrict__ b_f,
                            const float* __restrict__ bi_, const float* __restrict__ b_i,
                            const float* __restrict__ bu_, const float* __restrict__ b_u,
                            const float* __restrict__ bo_, const float* __restrict__ b_o,
                            const float* __restrict__ Wf, const float* __restrict__ Wi,
                            const float* __restrict__ Wu, const float* __restrict__ Wo,
                            float* __restrict__ bsum, float* __restrict__ bias2,
                            float* __restrict__ c_leaf)
{
  __shared__ float hl2[HD];
  int n = threadIdx.x;
  float sf = bf_[n] + b_f[n];
  float si = bi_[n] + b_i[n];
  float su = bu_[n] + b_u[n];
  float so = bo_[n] + b_o[n];
  bsum[n] = sf; bsum[HD + n] = si; bsum[2 * HD + n] = su; bsum[3 * HD + n] = so;
  float ig = 1.f / (1.f + expf(-si));
  float uu = tanhf(su);
  float cl = ig * uu;
  c_leaf[n] = cl;
  float hl = (1.f / (1.f + expf(-so))) * tanhf(cl);
  hl2[n] = 2.f * hl;
  __syncthreads();
  const float* Ws[4] = {Wf, Wi, Wu, Wo};
  for (int g = 0; g < 4; ++g) {
    const float* w = Ws[g] + n * KD;
    float s = 0.f;
    for (int k = 0; k < HD; k += 4) {
      floatx4 wv = *(const floatx4*)(w + k);
      floatx4 hv = *(const floatx4*)(&hl2[k]);
      s += wv[0] * hv[0] + wv[1] * hv[1] + wv[2] * hv[2] + wv[3] * hv[3];
    }
    bias2[g * HD + n] = bsum[g * HD + n] + s;
  }
}

// ---------------------------------------------------------------------------
// convert the 4 gate weights (fp32, [256][512]) to f16 packed [g][256][512]
// ---------------------------------------------------------------------------
__global__ void wcvt_kernel(const float* __restrict__ Wf, const float* __restrict__ Wi,
                            const float* __restrict__ Wu, const float* __restrict__ Wo,
                            _Float16* __restrict__ Wh)
{
  int idx = (blockIdx.x * 256 + threadIdx.x) * 4;
  int g = idx >> 17;
  int rem = idx & ((1 << 17) - 1);
  const float* src = (g == 0) ? Wf : (g == 1) ? Wi : (g == 2) ? Wu : Wo;
  floatx4 v = *(const floatx4*)(src + rem);
  half4v o;
  o[0] = (_Float16)v[0]; o[1] = (_Float16)v[1]; o[2] = (_Float16)v[2]; o[3] = (_Float16)v[3];
  *(half4v*)(Wh + idx) = o;
}

// ---------------------------------------------------------------------------
// fused level kernel: GEMM (4 gates) + LSTM cell update
// block = 256 threads = 4 waves; wave w computes gate w for a 64x64 tile
// grid = (M/64, 4) with M = 128 * 2^l ; n0 = blockIdx.y*64
// has_h==0 (leaf level): skip h chunk (folded into bias), K=256 (embeds only)
// ---------------------------------------------------------------------------
__global__ __launch_bounds__(256, 2)
void level_kernel(const _Float16* __restrict__ h_in,
                  const float* __restrict__ c_in,
                  const float* __restrict__ embed,
                  const _Float16* __restrict__ Wh,
                  const float* __restrict__ bias,
                  _Float16* __restrict__ h_out,
                  float* __restrict__ c_out,
                  int l, int child_stride, int has_h)
{
  __shared__ _Float16 As[64][256];   // XOR-swizzled 8-elem groups
  __shared__ float Zs[4][16][68];    // gate z exchange, padded rows

  const int cnt = 1 << l;
  const int cs = (2 << l) - 1;
  const int m0 = blockIdx.x * 64;
  const int n0 = blockIdx.y * 64;
  const int t = threadIdx.x;
  const int wave = t >> 6;
  const int lane = t & 63;
  const int lm = lane & 15;
  const int quad = lane >> 4;

  floatx4 acc[4][4] = {};

  // staging mapping: row sr = t>>2, quarter sq = t&3 (64 consecutive k)
  const int sr = t >> 2;
  const int sq = t & 3;
  const int sm = m0 + sr;
  const int sb = sm >> l;
  const int sj = sm & (cnt - 1);
  const int chbase = sb * 2 * cnt + 2 * sj;
  const long ebase = ((long)sb * 1023 + cs + 2 * sj) * 256;

  const _Float16* wg = Wh + (long)(wave * HD + n0) * KD;

  auto gemm_chunk = [&](int kbase) {
#pragma unroll
    for (int ks = 0; ks < 8; ++ks) {
      half8 bfr[4], afr[4];
#pragma unroll
      for (int nt = 0; nt < 4; ++nt)
        bfr[nt] = *(const half8*)(wg + (long)(nt * 16 + lm) * KD + kbase + ks * 32 + quad * 8);
#pragma unroll
      for (int mt = 0; mt < 4; ++mt) {
        int row = mt * 16 + lm;
        afr[mt] = *(const half8*)(&As[row][((ks * 4 + quad) ^ (row & 7)) * 8]);
      }
#pragma unroll
      for (int mt = 0; mt < 4; ++mt)
#pragma unroll
        for (int nt = 0; nt < 4; ++nt)
          acc[mt][nt] = __builtin_amdgcn_mfma_f32_16x16x32_f16(afr[mt], bfr[nt], acc[mt][nt], 0, 0, 0);
    }
  };

  if (has_h) {
    // chunk 0: h_sum (k 0..255)
    const _Float16* p0 = h_in + (long)chbase * child_stride;
    const _Float16* p1 = p0 + child_stride;
#pragma unroll
    for (int gi = 0; gi < 8; ++gi) {
      int kk = sq * 64 + gi * 8;
      half8 x0 = *(const half8*)(p0 + kk);
      half8 x1 = *(const half8*)(p1 + kk);
      half8 s;
#pragma unroll
      for (int e = 0; e < 8; ++e) s[e] = (_Float16)((float)x0[e] + (float)x1[e]);
      int gl = kk >> 3;
      *(half8*)(&As[sr][((gl ^ (sr & 7)) * 8)]) = s;
    }
    __syncthreads();
    gemm_chunk(0);
    __syncthreads();
  }

  // chunk 1: e_sum (k 256..511 of W)
  {
    const float* p0 = embed + ebase;
    const float* p1 = p0 + 256;
#pragma unroll
    for (int gi = 0; gi < 8; ++gi) {
      int kk = sq * 64 + gi * 8;
      half8 s;
#pragma unroll
      for (int h2 = 0; h2 < 2; ++h2) {
        floatx4 x0 = *(const floatx4*)(p0 + kk + h2 * 4);
        floatx4 x1 = *(const floatx4*)(p1 + kk + h2 * 4);
#pragma unroll
        for (int e = 0; e < 4; ++e) s[h2 * 4 + e] = (_Float16)(x0[e] + x1[e]);
      }
      int gl = kk >> 3;
      *(half8*)(&As[sr][((gl ^ (sr & 7)) * 8)]) = s;
    }
  }
  __syncthreads();
  gemm_chunk(256);

  // epilogue: per 16-row slab, exchange 4 gate z-tiles via LDS, apply cell
  const int r16 = t >> 4;        // 0..15
  const int cq = (t & 15) * 4;   // 0..60
#pragma unroll 1
  for (int mt = 0; mt < 4; ++mt) {
    __syncthreads();
#pragma unroll
    for (int nt = 0; nt < 4; ++nt)
#pragma unroll
      for (int e = 0; e < 4; ++e)
        Zs[wave][quad * 4 + e][nt * 16 + lm] = acc[mt][nt][e];
    __syncthreads();

    int mm = m0 + mt * 16 + r16;
    int b = mm >> l;
    int j = mm & (cnt - 1);
    int nglob = n0 + cq;

    floatx4 zf4 = *(const floatx4*)(&Zs[0][r16][cq]);
    floatx4 zi4 = *(const floatx4*)(&Zs[1][r16][cq]);
    floatx4 zu4 = *(const floatx4*)(&Zs[2][r16][cq]);
    floatx4 zo4 = *(const floatx4*)(&Zs[3][r16][cq]);
    floatx4 bf4 = *(const floatx4*)(bias + 0 * HD + nglob);
    floatx4 bi4 = *(const floatx4*)(bias + 1 * HD + nglob);
    floatx4 bu4 = *(const floatx4*)(bias + 2 * HD + nglob);
    floatx4 bo4 = *(const floatx4*)(bias + 3 * HD + nglob);

    long cbase = (long)(b * 2 * cnt + 2 * j) * child_stride + nglob;
    floatx4 c0v = *(const floatx4*)(c_in + cbase);
    floatx4 c1v = *(const floatx4*)(c_in + cbase + child_stride);

    half4v hv; floatx4 cv;
#pragma unroll
    for (int e = 0; e < 4; ++e) {
      float f  = sigmf_(zf4[e] + bf4[e]);
      float ig = sigmf_(zi4[e] + bi4[e]);
      float uu = tanhf_(zu4[e] + bu4[e]);
      float oo = sigmf_(zo4[e] + bo4[e]);
      float cn = ig * uu + f * (c0v[e] + c1v[e]);
      cv[e] = cn;
      hv[e] = (_Float16)(oo * tanhf_(cn));
    }
    long obase = ((long)(b * cnt + j)) * HD + nglob;
    *(floatx4*)(c_out + obase) = cv;
    *(half4v*)(h_out + obase) = hv;
  }
}

// ---------------------------------------------------------------------------
// head: tiny 128x256 @ 256x256 matmuls, one block per output row
// ---------------------------------------------------------------------------
__global__ void head12_kernel(const _Float16* __restrict__ hr,
                              const float* __restrict__ W1, const float* __restrict__ bl1,
                              const float* __restrict__ W2, const float* __restrict__ bl2,
                              float* __restrict__ t1, float* __restrict__ t2)
{
  __shared__ float a[HD];
  int b = blockIdx.x, n = threadIdx.x;
  a[n] = (float)hr[b * HD + n];
  __syncthreads();
  const float* w1 = W1 + n * HD;
  const float* w2 = W2 + n * HD;
  float s1 = bl1[n], s2 = bl2[n];
  for (int k = 0; k < HD; k += 4) {
    floatx4 av = *(const floatx4*)(&a[k]);
    floatx4 w1v = *(const floatx4*)(w1 + k);
    floatx4 w2v = *(const floatx4*)(w2 + k);
#pragma unroll
    for (int e = 0; e < 4; ++e) { s1 += av[e] * w1v[e]; s2 += av[e] * w2v[e]; }
  }
  t1[b * HD + n] = tanhf_(s1);
  t2[b * HD + n] = fmaxf(s2, 0.f);
}

__global__ void head3_kernel(const float* __restrict__ t2, const float* __restrict__ W3,
                             const float* __restrict__ bl3, const float* __restrict__ t1,
                             float* __restrict__ sb)
{
  __shared__ float a[HD];
  int b = blockIdx.x, n = threadIdx.x;
  a[n] = t2[b * HD + n];
  __syncthreads();
  const float* w = W3 + n * HD;
  float s = bl3[n];
  for (int k = 0; k < HD; k += 4) {
    floatx4 av = *(const floatx4*)(&a[k]);
    floatx4 wv = *(const floatx4*)(w + k);
#pragma unroll
    for (int e = 0; e < 4; ++e) s += av[e] * wv[e];
  }
  sb[b * HD + n] = t1[b * HD + n] + s;
}

__global__ void head4_kernel(const float* __restrict__ sv, const float* __restrict__ W4,
                             const float* __restrict__ bl4, float* __restrict__ out)
{
  __shared__ float a[HD];
  int b = blockIdx.x, n = threadIdx.x;
  a[n] = sv[b * HD + n];
  __syncthreads();
  const float* w = W4 + n * HD;
  float s = bl4[n];
  for (int k = 0; k < HD; k += 4) {
    floatx4 av = *(const floatx4*)(&a[k]);
    floatx4 wv = *(const floatx4*)(w + k);
#pragma unroll
    for (int e = 0; e < 4; ++e) s += av[e] * wv[e];
  }
  out[b * HD + n] = fmaxf(s, 0.f);
}

// ---------------------------------------------------------------------------
extern "C" void kernel_launch(void* const* d_in, const int* in_sizes, int n_in,
                              void* d_out, int out_size, void* d_ws, size_t ws_size,
                              hipStream_t stream)
{
  (void)in_sizes; (void)n_in; (void)out_size; (void)ws_size;
  const float* embed = (const float*)d_in[0];
  const float* Wf  = (const float*)d_in[1];
  const float* bf_ = (const float*)d_in[2];
  const float* b_f = (const float*)d_in[3];
  const float* Wi  = (const float*)d_in[4];
  const float* bi_ = (const float*)d_in[5];
  const float* b_i = (const float*)d_in[6];
  const float* Wu  = (const float*)d_in[7];
  const float* bu_ = (const float*)d_in[8];
  const float* b_u = (const float*)d_in[9];
  const float* Wo  = (const float*)d_in[10];
  const float* bo_ = (const float*)d_in[11];
  const float* b_o = (const float*)d_in[12];
  const float* W1  = (const float*)d_in[13];
  const float* bl1 = (const float*)d_in[14];
  const float* W2  = (const float*)d_in[15];
  const float* bl2 = (const float*)d_in[16];
  const float* W3  = (const float*)d_in[17];
  const float* bl3 = (const float*)d_in[18];
  const float* W4  = (const float*)d_in[19];
  const float* bl4 = (const float*)d_in[20];

  char* ws = (char*)d_ws;
  _Float16* Wh   = (_Float16*)(ws);                       // 1,048,576 B
  float* bsum    = (float*)(ws + 1048576);                // 4 KB
  float* bias2   = (float*)(ws + 1052672);                // 4 KB
  float* c_leaf  = (float*)(ws + 1056768);                // 1 KB
  _Float16* hbA  = (_Float16*)(ws + 1057792);             // 16,777,216 B (levels 8,6,4,2,0)
  _Float16* hbB  = (_Float16*)(ws + 17835008);            //  8,388,608 B (levels 7,5,3,1)
  float* cbA     = (float*)(ws + 26223616);               // 33,554,432 B
  float* cbB     = (float*)(ws + 59778048);               // 16,777,216 B
  float* t1      = (float*)(ws + 76555264);               // 128 KB
  float* t2      = (float*)(ws + 76686336);               // 128 KB
  float* sb      = (float*)(ws + 76817408);               // 128 KB

  prep_kernel<<<dim3(1), dim3(256), 0, stream>>>(bf_, b_f, bi_, b_i, bu_, b_u, bo_, b_o,
                                                 Wf, Wi, Wu, Wo, bsum, bias2, c_leaf);
  wcvt_kernel<<<dim3(512), dim3(256), 0, stream>>>(Wf, Wi, Wu, Wo, Wh);

  _Float16* houts[2] = {hbA, hbB};
  float* couts[2] = {cbA, cbB};
  int pp = 0;
  const _Float16* hin = hbA;   // unused at leaf level
  const float* cin = c_leaf;
  for (int l = 8; l >= 0; --l) {
    int leaf = (l == 8);
    dim3 grid((128 << l) / 64, 4);
    level_kernel<<<grid, dim3(256), 0, stream>>>(hin, cin, embed, Wh,
                                                 leaf ? bias2 : bsum,
                                                 houts[pp], couts[pp],
                                                 l, leaf ? 0 : 256, leaf ? 0 : 1);
    hin = houts[pp];
    cin = couts[pp];
    pp ^= 1;
  }

  head12_kernel<<<dim3(128), dim3(256), 0, stream>>>(hin, W1, bl1, W2, bl2, t1, t2);
  head3_kernel<<<dim3(128), dim3(256), 0, stream>>>(t2, W3, bl3, t1, sb);
  head4_kernel<<<dim3(128), dim3(256), 0, stream>>>(sb, W4, bl4, (float*)d_out);
}